// Round 10
// baseline (219.479 us; speedup 1.0000x reference)
//
#include <hip/hip_runtime.h>
#include <hip/hip_bf16.h>
#include <math.h>

#define NN 256
#define CC 128
#define HH 4
#define DD 32

typedef uint4 u128;
typedef __bf16 bf16x8 __attribute__((ext_vector_type(8)));
typedef float f32x4 __attribute__((ext_vector_type(4)));

#define LOG2E 1.4426950408889634f
#define QSC (0.17677669529663687f * LOG2E)   // 1/sqrt(32) * log2(e), folded into q

// ---------------------------------------------------------------------------
// K0 prep: biasM[j][k] = (mask[j][k] ? -inf : dscale*dm[j][k]) * log2e
//          Wt_qkv[n][k] = bf16(Wqkv[k][n]); Wt_out[n][k] = bf16(Wout[k][n])
// ---------------------------------------------------------------------------
__global__ __launch_bounds__(256) void prep_kernel(
    const float* __restrict__ dm, const int* __restrict__ mask,
    const float* __restrict__ dscale,
    const float* __restrict__ Wqkv, const float* __restrict__ Wout,
    float* __restrict__ biasM,
    __hip_bfloat16* __restrict__ Wt_qkv, __hip_bfloat16* __restrict__ Wt_out)
{
    const int b = blockIdx.x, t = threadIdx.x;
    if (b < 256) {
        int idx = b * 256 + t;                 // coalesced both sides
        biasM[idx] = mask[idx] ? -INFINITY : dscale[0] * dm[idx] * LOG2E;
    } else if (b < 448) {
        int idx = (b - 256) * 256 + t;         // [0, 49152)
        int n = idx >> 7, k = idx & 127;
        Wt_qkv[idx] = __float2bfloat16(Wqkv[(size_t)k * 384 + n]);
    } else {
        int idx = (b - 448) * 256 + t;         // [0, 16384)
        int n = idx >> 7, k = idx & 127;
        Wt_out[idx] = __float2bfloat16(Wout[(size_t)k * CC + n]);
    }
}

// ---------------------------------------------------------------------------
// K1: qkv = pair_rep @ Wqkv + bqkv  (MFMA, operand-swapped: C[n][m])
// 64m x 96n tile, grid (1024,4), 256 thr. A-tile only in LDS (17.4 KB);
// B-fragments straight from global (weights are L2-hot, no staging barrier).
// Wave w owns rows [w*16, w*16+16), all 96 n. q cols (n<128) pre-scaled QSC.
// ---------------------------------------------------------------------------
__global__ __launch_bounds__(256) void qkv_mfma_kernel(
    const float* __restrict__ A,              // [65536,128] fp32
    const __hip_bfloat16* __restrict__ Bt,    // [384,128] bf16 (transposed W)
    const float* __restrict__ bias,           // [384]
    __hip_bfloat16* __restrict__ out)         // [65536,384]
{
    __shared__ __align__(16) __hip_bfloat16 As[64][136];
    const int t = threadIdx.x;
    const int m0 = blockIdx.x * 64;
    const int n0 = blockIdx.y * 96;

    #pragma unroll
    for (int it = 0; it < 8; ++it) {           // A: 64x128 fp32 -> bf16 LDS
        int idx = it * 256 + t;
        int r = idx >> 5, c4 = (idx & 31) * 4;
        float4 v = *(const float4*)(A + (size_t)(m0 + r) * CC + c4);
        __hip_bfloat162 a01 = __float22bfloat162_rn(float2{v.x, v.y});
        __hip_bfloat162 a23 = __float22bfloat162_rn(float2{v.z, v.w});
        uint2 pk;
        pk.x = *(unsigned int*)&a01;
        pk.y = *(unsigned int*)&a23;
        *(uint2*)&As[r][c4] = pk;
    }
    __syncthreads();

    const int w = t >> 6, lane = t & 63;
    const int n16 = lane & 15, quad = lane >> 4;
    const int mw = w * 16;

    bf16x8 pf[4];                              // B-operand: pair rows [m][k]
    #pragma unroll
    for (int ks = 0; ks < 4; ++ks)
        pf[ks] = *(const bf16x8*)&As[mw + n16][ks * 32 + quad * 8];

    f32x4 acc[6];
    #pragma unroll
    for (int nt = 0; nt < 6; ++nt) acc[nt] = (f32x4){0.f, 0.f, 0.f, 0.f};

    #pragma unroll
    for (int nt = 0; nt < 6; ++nt) {
        const __hip_bfloat16* brow = Bt + (size_t)(n0 + nt * 16 + n16) * CC;
        #pragma unroll
        for (int ks = 0; ks < 4; ++ks) {
            bf16x8 wf = *(const bf16x8*)(brow + ks * 32 + quad * 8);
            acc[nt] = __builtin_amdgcn_mfma_f32_16x16x32_bf16(wf, pf[ks], acc[nt], 0, 0, 0);
        }
    }

    // C[row = n-local = quad*4+r, col = m-local = n16]
    #pragma unroll
    for (int nt = 0; nt < 6; ++nt) {
        int nbase = n0 + nt * 16 + quad * 4;
        float4 b4 = *(const float4*)(bias + nbase);
        float sc = (nbase < CC) ? QSC : 1.0f;  // group of 4 never straddles 128
        int m = m0 + mw + n16;
        __hip_bfloat162 h01 = __float22bfloat162_rn(float2{(acc[nt][0] + b4.x) * sc, (acc[nt][1] + b4.y) * sc});
        __hip_bfloat162 h23 = __float22bfloat162_rn(float2{(acc[nt][2] + b4.z) * sc, (acc[nt][3] + b4.w) * sc});
        uint2 pk;
        pk.x = *(unsigned int*)&h01;
        pk.y = *(unsigned int*)&h23;
        *(uint2*)&out[(size_t)m * 384 + nbase] = pk;
    }
}

// ---------------------------------------------------------------------------
// K2: MFMA attention, S^T formulation, 512 threads (8 waves), 16 waves/CU.
//   All 512 threads stage: thread pair (r=t>>1, c=t&1), thread handles
//   chunks 2c,2c+1 = elements c*16..c*16+15 of each 32-elem K/V row.
//   S^T = mfma(K-frag, Q-frag, C=bias); raw exp2 (no max, fp32-safe);
//   P through LDS in two k-halves; PV accumulates across passes.
// ---------------------------------------------------------------------------
__global__ __launch_bounds__(512, 4) void attn_mfma_kernel(
    const __hip_bfloat16* __restrict__ qkv,   // [65536,384]
    const float* __restrict__ biasM,          // [256,256] *log2e
    __hip_bfloat16* __restrict__ attn_out)    // [65536,128]
{
    __shared__ __align__(16) __hip_bfloat16 Ks[NN][40];      // 20.0 KB
    __shared__ __align__(16) __hip_bfloat16 VTs[DD][264];    // 16.5 KB
    __shared__ __align__(16) __hip_bfloat16 Ps[8][16][136];  // 34.0 KB (k-half)

    const int bi = blockIdx.x;
    const int i = bi >> 2, h = bi & 3;
    const int t = threadIdx.x;

    {   // stage K rows + V^T: half-row per thread (elements c*16 .. c*16+15)
        const int r = t >> 1, c = t & 1;
        const __hip_bfloat16* base = qkv + (size_t)(i * NN + r) * 384 + h * DD;
        const u128* ksrc = (const u128*)(base + CC);
        const u128* vsrc = (const u128*)(base + 2 * CC);
        u128 k0 = ksrc[2 * c], k1 = ksrc[2 * c + 1];
        u128 v0 = vsrc[2 * c], v1 = vsrc[2 * c + 1];
        u128* kdst = (u128*)&Ks[r][0];
        kdst[2 * c] = k0;
        kdst[2 * c + 1] = k1;
        __align__(16) __hip_bfloat16 vh[16];
        *(u128*)&vh[0] = v0;
        *(u128*)&vh[8] = v1;
        #pragma unroll
        for (int e = 0; e < 16; ++e) VTs[c * 16 + e][r] = vh[e];
    }
    __syncthreads();

    const int w = t >> 6, lane = t & 63;
    const int n16 = lane & 15, quad = lane >> 4;

    #pragma unroll
    for (int jt = 0; jt < 2; ++jt) {
        const int j0 = w * 32 + jt * 16;
        const int j = j0 + n16;                // this lane's softmax column

        // Q B-frag for row j
        bf16x8 qa = *(const bf16x8*)(qkv + (size_t)(i * NN + j) * 384 + h * DD + quad * 8);
        const float4* brow = (const float4*)(biasM + (size_t)j * NN);

        // S^T tiles with bias in C: s[kt][r] = S[k=kt*16+quad*4+r][j]
        f32x4 s[16];
        #pragma unroll
        for (int kt = 0; kt < 16; ++kt) {
            bf16x8 kb = *(const bf16x8*)&Ks[kt * 16 + n16][quad * 8];
            float4 b4 = brow[kt * 4 + quad];
            s[kt] = __builtin_amdgcn_mfma_f32_16x16x32_bf16(
                kb, qa, (f32x4){b4.x, b4.y, b4.z, b4.w}, 0, 0, 0);
        }

        // raw exp2 (no max) + packed P write, two k-halves; PV across passes
        f32x4 sm = {0.f, 0.f, 0.f, 0.f};
        f32x4 o[2] = {(f32x4){0.f, 0.f, 0.f, 0.f}, (f32x4){0.f, 0.f, 0.f, 0.f}};
        #pragma unroll
        for (int pass = 0; pass < 2; ++pass) {
            #pragma unroll
            for (int kt8 = 0; kt8 < 8; ++kt8) {
                int kt = pass * 8 + kt8;
                float p0 = exp2f(s[kt][0]);
                float p1 = exp2f(s[kt][1]);
                float p2 = exp2f(s[kt][2]);
                float p3 = exp2f(s[kt][3]);
                sm[0] += p0; sm[1] += p1; sm[2] += p2; sm[3] += p3;
                __hip_bfloat162 h01 = __float22bfloat162_rn(float2{p0, p1});
                __hip_bfloat162 h23 = __float22bfloat162_rn(float2{p2, p3});
                uint2 pk;
                pk.x = *(unsigned int*)&h01;
                pk.y = *(unsigned int*)&h23;
                *(uint2*)&Ps[w][n16][kt8 * 16 + quad * 4] = pk;
            }
            // PV for this k-half (per-wave in-order LDS: reads see the writes)
            #pragma unroll
            for (int c = 0; c < 4; ++c) {
                bf16x8 pa = *(const bf16x8*)&Ps[w][n16][c * 32 + quad * 8];
                #pragma unroll
                for (int dt = 0; dt < 2; ++dt) {
                    bf16x8 vb = *(const bf16x8*)&VTs[dt * 16 + n16][pass * 128 + c * 32 + quad * 8];
                    o[dt] = __builtin_amdgcn_mfma_f32_16x16x32_bf16(vb, pa, o[dt], 0, 0, 0);
                }
            }
        }
        float sum = (sm[0] + sm[1]) + (sm[2] + sm[3]);
        sum += __shfl_xor(sum, 16);
        sum += __shfl_xor(sum, 32);
        float inv = 1.0f / sum;

        // store: column j (same lane as softmax -> own inv), packed d
        __hip_bfloat16* obase = attn_out + (size_t)(i * NN + j) * CC + h * DD + quad * 4;
        #pragma unroll
        for (int dt = 0; dt < 2; ++dt) {
            __hip_bfloat162 h01 = __float22bfloat162_rn(float2{o[dt][0] * inv, o[dt][1] * inv});
            __hip_bfloat162 h23 = __float22bfloat162_rn(float2{o[dt][2] * inv, o[dt][3] * inv});
            uint2 pk;
            pk.x = *(unsigned int*)&h01;
            pk.y = *(unsigned int*)&h23;
            *(uint2*)(obase + dt * 16) = pk;
        }
    }
}

// ---------------------------------------------------------------------------
// K3: out = attn_out @ Wout + bout  (MFMA, operand-swapped -> float4 stores)
// 64-row tiles, grid 1024, 256 thr; A-only LDS (17.4 KB), B from global/L2.
// Wave w: rows [w*16,+16), all 128 n: 8nt x 4ks = 32 MFMAs.
// ---------------------------------------------------------------------------
__global__ __launch_bounds__(256) void out_mfma_kernel(
    const __hip_bfloat16* __restrict__ A,     // [65536,128] bf16
    const __hip_bfloat16* __restrict__ Bt,    // [128,128] bf16 (transposed W)
    const float* __restrict__ bias,           // [128]
    float* __restrict__ out)                  // [65536,128]
{
    __shared__ __align__(16) __hip_bfloat16 As[64][136];
    const int t = threadIdx.x;
    const int m0 = blockIdx.x * 64;

    #pragma unroll
    for (int it = 0; it < 4; ++it) {           // A: 64x128 bf16 = 1024 u128
        int idx = it * 256 + t;
        int r = idx >> 4, c8 = (idx & 15) * 8;
        *(u128*)&As[r][c8] = *(const u128*)(A + (size_t)(m0 + r) * CC + c8);
    }
    __syncthreads();

    const int w = t >> 6, lane = t & 63;
    const int n16 = lane & 15, quad = lane >> 4;
    const int mw = w * 16;

    bf16x8 pf[4];
    #pragma unroll
    for (int ks = 0; ks < 4; ++ks)
        pf[ks] = *(const bf16x8*)&As[mw + n16][ks * 32 + quad * 8];

    f32x4 acc[8];
    #pragma unroll
    for (int nt = 0; nt < 8; ++nt) acc[nt] = (f32x4){0.f, 0.f, 0.f, 0.f};

    #pragma unroll
    for (int nt = 0; nt < 8; ++nt) {
        const __hip_bfloat16* brow = Bt + (size_t)(nt * 16 + n16) * CC;
        #pragma unroll
        for (int ks = 0; ks < 4; ++ks) {
            bf16x8 wf = *(const bf16x8*)(brow + ks * 32 + quad * 8);
            acc[nt] = __builtin_amdgcn_mfma_f32_16x16x32_bf16(wf, pf[ks], acc[nt], 0, 0, 0);
        }
    }

    #pragma unroll
    for (int nt = 0; nt < 8; ++nt) {
        int nbase = nt * 16 + quad * 4;
        float4 b4 = *(const float4*)(bias + nbase);
        int m = m0 + mw + n16;
        float4 ov;
        ov.x = acc[nt][0] + b4.x;
        ov.y = acc[nt][1] + b4.y;
        ov.z = acc[nt][2] + b4.z;
        ov.w = acc[nt][3] + b4.w;
        *(float4*)&out[(size_t)m * CC + nbase] = ov;
    }
}

// ---------------------------------------------------------------------------
extern "C" void kernel_launch(void* const* d_in, const int* in_sizes, int n_in,
                              void* d_out, int out_size, void* d_ws, size_t ws_size,
                              hipStream_t stream) {
    const float* pair_rep = (const float*)d_in[0];
    const float* dm       = (const float*)d_in[1];
    const float* Wqkv     = (const float*)d_in[2];
    const float* bqkv     = (const float*)d_in[3];
    const float* Wout     = (const float*)d_in[4];
    const float* bout     = (const float*)d_in[5];
    const float* dscale   = (const float*)d_in[6];
    const int*   mask     = (const int*)d_in[7];
    float* out = (float*)d_out;

    // ws: biasM[256KB] | Wt_qkv[96KB] | Wt_out[32KB] | qkv[48MB] | attn[16MB]
    char* p = (char*)d_ws;
    float* biasM = (float*)p;                 p += (size_t)NN * NN * 4;
    __hip_bfloat16* Wt_qkv = (__hip_bfloat16*)p;  p += (size_t)384 * CC * 2;
    __hip_bfloat16* Wt_out = (__hip_bfloat16*)p;  p += (size_t)CC * CC * 2;
    __hip_bfloat16* qkv  = (__hip_bfloat16*)p;    p += (size_t)65536 * 384 * 2;
    __hip_bfloat16* attn = (__hip_bfloat16*)p;

    prep_kernel<<<dim3(512), dim3(256), 0, stream>>>(dm, mask, dscale, Wqkv, Wout, biasM, Wt_qkv, Wt_out);
    qkv_mfma_kernel<<<dim3(1024, 4), dim3(256), 0, stream>>>(pair_rep, Wt_qkv, bqkv, qkv);
    attn_mfma_kernel<<<dim3(1024), dim3(512), 0, stream>>>(qkv, biasM, attn);
    out_mfma_kernel<<<dim3(1024), dim3(256), 0, stream>>>(attn, Wt_out, bout, out);
}